// Round 1
// baseline (26998.257 us; speedup 1.0000x reference)
//
#include <hip/hip_runtime.h>
#include <hip/hip_bf16.h>

// Problem constants
#define BB 32     // batch
#define TT 512    // time
#define AA 512    // acoustic dim
#define EE 256    // emb dim
#define HH 320    // hidden
#define VV 8192   // vocab
#define KIN 768   // A+E
#define G4 1280   // 4*H

__device__ __forceinline__ float sigm(float x) { return 1.f / (1.f + expf(-x)); }

// ---------------- Stage A: X[r=t*B+b][j] = tanh(concat(a,e) . W_in[j,:] + b_in[j]) ----------------
__global__ __launch_bounds__(320) void stage_x(const float* __restrict__ ac,
                                               const int* __restrict__ tok,
                                               const float* __restrict__ emb,
                                               const float* __restrict__ Win,
                                               const float* __restrict__ bin,
                                               float* __restrict__ X) {
    __shared__ float xs[8][KIN];
    const int r0 = blockIdx.x * 8;
    const int tid = threadIdx.x;
    for (int rr = 0; rr < 8; ++rr) {
        const int r = r0 + rr;
        const int t = r >> 5;       // r / 32
        const int b = r & 31;       // r % 32
        const int tk = tok[b * TT + t];
        for (int k = tid; k < KIN; k += 320) {
            float v;
            if (k < AA) v = ac[((size_t)b * TT + t) * AA + k];
            else        v = (tk == 0) ? 0.f : emb[(size_t)tk * EE + (k - AA)];
            xs[rr][k] = v;
        }
    }
    __syncthreads();
    const int j = tid;  // 0..319
    float acc[8];
    const float bj = bin[j];
#pragma unroll
    for (int rr = 0; rr < 8; ++rr) acc[rr] = bj;
    const float* w = Win + (size_t)j * KIN;
    for (int k = 0; k < KIN; ++k) {
        const float wv = w[k];
#pragma unroll
        for (int rr = 0; rr < 8; ++rr) acc[rr] += wv * xs[rr][k];
    }
#pragma unroll
    for (int rr = 0; rr < 8; ++rr)
        X[(size_t)(r0 + rr) * HH + j] = tanhf(acc[rr]);
}

// ---------------- Stage B: G[r][j] = X[r,:] . W_ih[j,:] + b_ih[j] + b_hh[j] ----------------
__global__ __launch_bounds__(256) void stage_gin(const float* __restrict__ X,
                                                 const float* __restrict__ Wih,
                                                 const float* __restrict__ bih,
                                                 const float* __restrict__ bhh,
                                                 float* __restrict__ G) {
    __shared__ float xs[8][HH];
    const int r0 = blockIdx.x * 8;
    const int tid = threadIdx.x;
    for (int rr = 0; rr < 8; ++rr)
        for (int k = tid; k < HH; k += 256)
            xs[rr][k] = X[(size_t)(r0 + rr) * HH + k];
    __syncthreads();
    for (int p = 0; p < 5; ++p) {
        const int j = tid + 256 * p;  // 0..1279
        const float bias = bih[j] + bhh[j];
        float acc[8];
#pragma unroll
        for (int rr = 0; rr < 8; ++rr) acc[rr] = bias;
        const float* w = Wih + (size_t)j * HH;
        for (int k = 0; k < HH; ++k) {
            const float wv = w[k];
#pragma unroll
            for (int rr = 0; rr < 8; ++rr) acc[rr] += wv * xs[rr][k];
        }
#pragma unroll
        for (int rr = 0; rr < 8; ++rr)
            G[(size_t)(r0 + rr) * G4 + j] = acc[rr];
    }
}

// ---------------- Stage C: sequential LSTM recurrence, one block per batch ----------------
__global__ __launch_bounds__(1024) void stage_rec(const float* __restrict__ G,
                                                  const float* __restrict__ Whh,
                                                  float* __restrict__ Hs) {
    const int b = blockIdx.x;   // 0..31
    const int tid = threadIdx.x;
    __shared__ float h[HH];
    __shared__ float c[HH];
    __shared__ float gates[G4];
    if (tid < HH) { h[tid] = 0.f; c[tid] = 0.f; }
    __syncthreads();
    for (int t = 0; t < TT; ++t) {
        const float* g_in = G + ((size_t)t * BB + b) * G4;
        {
            const int j = tid;  // 0..1023
            const float* w = Whh + (size_t)j * HH;
            float acc = g_in[j];
            for (int k = 0; k < HH; ++k) acc += w[k] * h[k];
            gates[j] = acc;
        }
        if (tid < G4 - 1024) {
            const int j = 1024 + tid;
            const float* w = Whh + (size_t)j * HH;
            float acc = g_in[j];
            for (int k = 0; k < HH; ++k) acc += w[k] * h[k];
            gates[j] = acc;
        }
        __syncthreads();
        if (tid < HH) {
            const float gi = gates[tid];
            const float gf = gates[HH + tid];
            const float gg = gates[2 * HH + tid];
            const float go = gates[3 * HH + tid];
            const float cn = sigm(gf) * c[tid] + sigm(gi) * tanhf(gg);
            const float hn = sigm(go) * tanhf(cn);
            c[tid] = cn;
            h[tid] = hn;
            Hs[((size_t)t * BB + b) * HH + tid] = hn;
        }
        __syncthreads();
    }
}

// ---------------- Stage D: logits[m=b*T+t][v] = Hs[t*B+b,:] . W_out[v,:] + b_out[v] ----------------
__global__ __launch_bounds__(256) void stage_logits(const float* __restrict__ Hs,
                                                    const float* __restrict__ Wout,
                                                    const float* __restrict__ bout,
                                                    float* __restrict__ out) {
    __shared__ float hs[16][HH];
    const int m0 = blockIdx.y * 16;
    const int v0 = blockIdx.x * 256;
    const int tid = threadIdx.x;
    for (int rr = 0; rr < 16; ++rr) {
        const int m = m0 + rr;
        const int bb = m >> 9;      // m / T
        const int t2 = m & 511;     // m % T
        for (int k = tid; k < HH; k += 256)
            hs[rr][k] = Hs[((size_t)t2 * BB + bb) * HH + k];
    }
    __syncthreads();
    const int v = v0 + tid;
    float acc[16];
    const float bv = bout[v];
#pragma unroll
    for (int rr = 0; rr < 16; ++rr) acc[rr] = bv;
    const float* w = Wout + (size_t)v * HH;
    for (int k = 0; k < HH; ++k) {
        const float wv = w[k];
#pragma unroll
        for (int rr = 0; rr < 16; ++rr) acc[rr] += wv * hs[rr][k];
    }
#pragma unroll
    for (int rr = 0; rr < 16; ++rr)
        out[(size_t)(m0 + rr) * VV + v] = acc[rr];
}

// ---------------- Stage E: in-place log_softmax over V per row ----------------
__global__ __launch_bounds__(256) void stage_lsm(float* __restrict__ out) {
    __shared__ float buf[VV];
    __shared__ float red[16];
    const size_t m = blockIdx.x;
    float* row = out + m * VV;
    const int tid = threadIdx.x;

    float mx = -INFINITY;
    for (int k = tid; k < VV; k += 256) {
        const float v = row[k];
        buf[k] = v;
        mx = fmaxf(mx, v);
    }
#pragma unroll
    for (int off = 32; off > 0; off >>= 1) mx = fmaxf(mx, __shfl_down(mx, off, 64));
    if ((tid & 63) == 0) red[tid >> 6] = mx;
    __syncthreads();
    if (tid == 0) {
        float m2 = red[0];
        for (int i = 1; i < 4; ++i) m2 = fmaxf(m2, red[i]);
        red[0] = m2;
    }
    __syncthreads();
    mx = red[0];

    float s = 0.f;
    for (int k = tid; k < VV; k += 256) s += expf(buf[k] - mx);
#pragma unroll
    for (int off = 32; off > 0; off >>= 1) s += __shfl_down(s, off, 64);
    if ((tid & 63) == 0) red[8 + (tid >> 6)] = s;
    __syncthreads();
    if (tid == 0) {
        float s2 = 0.f;
        for (int i = 0; i < 4; ++i) s2 += red[8 + i];
        red[8] = logf(s2);
    }
    __syncthreads();
    const float lse = mx + red[8];
    for (int k = tid; k < VV; k += 256) row[k] = buf[k] - lse;
}

extern "C" void kernel_launch(void* const* d_in, const int* in_sizes, int n_in,
                              void* d_out, int out_size, void* d_ws, size_t ws_size,
                              hipStream_t stream) {
    const float* ac   = (const float*)d_in[0];
    const int*   tok  = (const int*)d_in[1];
    const float* emb  = (const float*)d_in[2];
    const float* Win  = (const float*)d_in[3];
    const float* bin  = (const float*)d_in[4];
    const float* Wih  = (const float*)d_in[5];
    const float* Whh  = (const float*)d_in[6];
    const float* bih  = (const float*)d_in[7];
    const float* bhh  = (const float*)d_in[8];
    const float* Wout = (const float*)d_in[9];
    const float* bout = (const float*)d_in[10];
    float* out = (float*)d_out;

    float* X  = (float*)d_ws;                       // [T*B, H]   = 21 MB
    float* G  = X + (size_t)TT * BB * HH;           // [T*B, 4H]  = 84 MB
    float* Hs = G + (size_t)TT * BB * G4;           // [T*B, H]   = 21 MB

    stage_x<<<dim3(TT * BB / 8), dim3(320), 0, stream>>>(ac, tok, emb, Win, bin, X);
    stage_gin<<<dim3(TT * BB / 8), dim3(256), 0, stream>>>(X, Wih, bih, bhh, G);
    stage_rec<<<dim3(BB), dim3(1024), 0, stream>>>(G, Whh, Hs);
    stage_logits<<<dim3(VV / 256, TT * BB / 16), dim3(256), 0, stream>>>(Hs, Wout, bout, out);
    stage_lsm<<<dim3(TT * BB), dim3(256), 0, stream>>>(out);
}

// Round 2
// 26132.880 us; speedup vs baseline: 1.0331x; 1.0331x over previous
//
#include <hip/hip_runtime.h>
#include <hip/hip_bf16.h>

// Problem constants
#define BB 32     // batch
#define TT 512    // time
#define AA 512    // acoustic dim
#define EE 256    // emb dim
#define HH 320    // hidden
#define VV 8192   // vocab
#define KIN 768   // A+E
#define G4 1280   // 4*H

__device__ __forceinline__ float sigm(float x) { return 1.f / (1.f + expf(-x)); }

// ---------------- Stage A: X[r=t*B+b][j] = tanh(concat(a,e) . W_in[j,:] + b_in[j]) ----------------
__global__ __launch_bounds__(320) void stage_x(const float* __restrict__ ac,
                                               const int* __restrict__ tok,
                                               const float* __restrict__ emb,
                                               const float* __restrict__ Win,
                                               const float* __restrict__ bin,
                                               float* __restrict__ X) {
    __shared__ float xs[8][KIN];
    const int r0 = blockIdx.x * 8;
    const int tid = threadIdx.x;
    // stage 8 rows of concat(a, emb) into LDS, float4-vectorized
    for (int rr = 0; rr < 8; ++rr) {
        const int r = r0 + rr;
        const int t = r >> 5;       // r / 32
        const int b = r & 31;       // r % 32
        const int tk = tok[b * TT + t];
        const float4* ac4  = (const float4*)(ac + ((size_t)b * TT + t) * AA);
        const float4* emb4 = (const float4*)(emb + (size_t)tk * EE);
        float4* xs4 = (float4*)&xs[rr][0];
        for (int k4 = tid; k4 < KIN / 4; k4 += 320) {
            float4 v;
            if (k4 < AA / 4) v = ac4[k4];
            else if (tk == 0) v = make_float4(0.f, 0.f, 0.f, 0.f);
            else v = emb4[k4 - AA / 4];
            xs4[k4] = v;
        }
    }
    __syncthreads();
    const int j = tid;  // 0..319
    float acc[8];
    const float bj = bin[j];
#pragma unroll
    for (int rr = 0; rr < 8; ++rr) acc[rr] = bj;
    const float4* w4 = (const float4*)(Win + (size_t)j * KIN);
#pragma unroll 4
    for (int k4 = 0; k4 < KIN / 4; ++k4) {
        const float4 wv = w4[k4];
#pragma unroll
        for (int rr = 0; rr < 8; ++rr) {
            const float4 xv = ((const float4*)&xs[rr][0])[k4];  // broadcast
            acc[rr] += wv.x * xv.x + wv.y * xv.y + wv.z * xv.z + wv.w * xv.w;
        }
    }
#pragma unroll
    for (int rr = 0; rr < 8; ++rr)
        X[(size_t)(r0 + rr) * HH + j] = tanhf(acc[rr]);
}

// ---------------- Stage B: G[r][j] = X[r,:] . W_ih[j,:] + b_ih[j] + b_hh[j] ----------------
__global__ __launch_bounds__(256) void stage_gin(const float* __restrict__ X,
                                                 const float* __restrict__ Wih,
                                                 const float* __restrict__ bih,
                                                 const float* __restrict__ bhh,
                                                 float* __restrict__ G) {
    __shared__ float xs[8][HH];
    const int r0 = blockIdx.x * 8;
    const int tid = threadIdx.x;
    {
        const float4* src = (const float4*)(X + (size_t)r0 * HH);
        float4* dst = (float4*)&xs[0][0];
        for (int k4 = tid; k4 < 8 * HH / 4; k4 += 256) dst[k4] = src[k4];
    }
    __syncthreads();
    for (int p = 0; p < 5; ++p) {
        const int j = tid + 256 * p;  // 0..1279
        const float bias = bih[j] + bhh[j];
        float acc[8];
#pragma unroll
        for (int rr = 0; rr < 8; ++rr) acc[rr] = bias;
        const float4* w4 = (const float4*)(Wih + (size_t)j * HH);
#pragma unroll 4
        for (int k4 = 0; k4 < HH / 4; ++k4) {
            const float4 wv = w4[k4];
#pragma unroll
            for (int rr = 0; rr < 8; ++rr) {
                const float4 xv = ((const float4*)&xs[rr][0])[k4];  // broadcast
                acc[rr] += wv.x * xv.x + wv.y * xv.y + wv.z * xv.z + wv.w * xv.w;
            }
        }
#pragma unroll
        for (int rr = 0; rr < 8; ++rr)
            G[(size_t)(r0 + rr) * G4 + j] = acc[rr];
    }
}

// ---------------- Stage C: sequential LSTM recurrence, one block per batch ----------------
// 1024 threads: thread t computes gate row t; threads 0..255 additionally row 1024+t.
// Weight rows walked as float4 (one 128B line = 8 back-to-back loads -> L1-friendly).
__global__ __launch_bounds__(1024) void stage_rec(const float* __restrict__ G,
                                                  const float* __restrict__ Whh,
                                                  float* __restrict__ Hs) {
    const int b = blockIdx.x;   // 0..31
    const int tid = threadIdx.x;
    __shared__ float h[HH];
    __shared__ float c[HH];
    __shared__ float gates[G4];
    if (tid < HH) { h[tid] = 0.f; c[tid] = 0.f; }
    __syncthreads();
    const int j0 = tid;
    const int j1 = 1024 + tid;              // valid for tid < 256
    const bool two = (tid < G4 - 1024);
    const float4* w0 = (const float4*)(Whh + (size_t)j0 * HH);
    const float4* w1 = (const float4*)(Whh + (size_t)j1 * HH);
    const float4* h4 = (const float4*)h;
    for (int t = 0; t < TT; ++t) {
        const float* g_in = G + ((size_t)t * BB + b) * G4;
        float a0 = g_in[j0];
        float a1 = two ? g_in[j1] : 0.f;
        if (two) {
#pragma unroll 8
            for (int k4 = 0; k4 < HH / 4; ++k4) {
                const float4 hv = h4[k4];   // LDS broadcast
                const float4 x0 = w0[k4];
                const float4 x1 = w1[k4];
                a0 += x0.x * hv.x + x0.y * hv.y + x0.z * hv.z + x0.w * hv.w;
                a1 += x1.x * hv.x + x1.y * hv.y + x1.z * hv.z + x1.w * hv.w;
            }
        } else {
#pragma unroll 8
            for (int k4 = 0; k4 < HH / 4; ++k4) {
                const float4 hv = h4[k4];
                const float4 x0 = w0[k4];
                a0 += x0.x * hv.x + x0.y * hv.y + x0.z * hv.z + x0.w * hv.w;
            }
        }
        gates[j0] = a0;
        if (two) gates[j1] = a1;
        __syncthreads();
        if (tid < HH) {
            const float gi = gates[tid];
            const float gf = gates[HH + tid];
            const float gg = gates[2 * HH + tid];
            const float go = gates[3 * HH + tid];
            const float cn = sigm(gf) * c[tid] + sigm(gi) * tanhf(gg);
            const float hn = sigm(go) * tanhf(cn);
            c[tid] = cn;
            h[tid] = hn;
            Hs[((size_t)t * BB + b) * HH + tid] = hn;
        }
        __syncthreads();
    }
}

// ---------------- Stage D: logits[m=b*T+t][v] = Hs[t*B+b,:] . W_out[v,:] + b_out[v] ----------------
__global__ __launch_bounds__(256) void stage_logits(const float* __restrict__ Hs,
                                                    const float* __restrict__ Wout,
                                                    const float* __restrict__ bout,
                                                    float* __restrict__ out) {
    __shared__ float hs[16][HH];
    const int m0 = blockIdx.y * 16;
    const int v0 = blockIdx.x * 256;
    const int tid = threadIdx.x;
    for (int rr = 0; rr < 16; ++rr) {
        const int m = m0 + rr;
        const int bb = m >> 9;      // m / T
        const int t2 = m & 511;     // m % T
        const float4* src = (const float4*)(Hs + ((size_t)t2 * BB + bb) * HH);
        float4* dst = (float4*)&hs[rr][0];
        for (int k4 = tid; k4 < HH / 4; k4 += 256) dst[k4] = src[k4];
    }
    __syncthreads();
    const int v = v0 + tid;
    float acc[16];
    const float bv = bout[v];
#pragma unroll
    for (int rr = 0; rr < 16; ++rr) acc[rr] = bv;
    const float4* w4 = (const float4*)(Wout + (size_t)v * HH);
#pragma unroll 2
    for (int k4 = 0; k4 < HH / 4; ++k4) {
        const float4 wv = w4[k4];
#pragma unroll
        for (int rr = 0; rr < 16; ++rr) {
            const float4 hv = ((const float4*)&hs[rr][0])[k4];  // broadcast
            acc[rr] += wv.x * hv.x + wv.y * hv.y + wv.z * hv.z + wv.w * hv.w;
        }
    }
#pragma unroll
    for (int rr = 0; rr < 16; ++rr)
        out[(size_t)(m0 + rr) * VV + v] = acc[rr];
}

// ---------------- Stage E: in-place log_softmax over V per row ----------------
__global__ __launch_bounds__(256) void stage_lsm(float* __restrict__ out) {
    __shared__ float buf[VV];
    __shared__ float red[16];
    const size_t m = blockIdx.x;
    float4* row4 = (float4*)(out + m * VV);
    float4* buf4 = (float4*)buf;
    const int tid = threadIdx.x;

    float mx = -INFINITY;
    for (int k4 = tid; k4 < VV / 4; k4 += 256) {
        const float4 v = row4[k4];
        buf4[k4] = v;
        mx = fmaxf(mx, fmaxf(fmaxf(v.x, v.y), fmaxf(v.z, v.w)));
    }
#pragma unroll
    for (int off = 32; off > 0; off >>= 1) mx = fmaxf(mx, __shfl_down(mx, off, 64));
    if ((tid & 63) == 0) red[tid >> 6] = mx;
    __syncthreads();
    if (tid == 0) {
        float m2 = red[0];
        for (int i = 1; i < 4; ++i) m2 = fmaxf(m2, red[i]);
        red[0] = m2;
    }
    __syncthreads();
    mx = red[0];

    float s = 0.f;
    for (int k4 = tid; k4 < VV / 4; k4 += 256) {
        const float4 v = buf4[k4];
        s += expf(v.x - mx) + expf(v.y - mx) + expf(v.z - mx) + expf(v.w - mx);
    }
#pragma unroll
    for (int off = 32; off > 0; off >>= 1) s += __shfl_down(s, off, 64);
    if ((tid & 63) == 0) red[8 + (tid >> 6)] = s;
    __syncthreads();
    if (tid == 0) {
        float s2 = 0.f;
        for (int i = 0; i < 4; ++i) s2 += red[8 + i];
        red[8] = logf(s2);
    }
    __syncthreads();
    const float lse = mx + red[8];
    for (int k4 = tid; k4 < VV / 4; k4 += 256) {
        float4 v = buf4[k4];
        v.x -= lse; v.y -= lse; v.z -= lse; v.w -= lse;
        row4[k4] = v;
    }
}

extern "C" void kernel_launch(void* const* d_in, const int* in_sizes, int n_in,
                              void* d_out, int out_size, void* d_ws, size_t ws_size,
                              hipStream_t stream) {
    const float* ac   = (const float*)d_in[0];
    const int*   tok  = (const int*)d_in[1];
    const float* emb  = (const float*)d_in[2];
    const float* Win  = (const float*)d_in[3];
    const float* bin  = (const float*)d_in[4];
    const float* Wih  = (const float*)d_in[5];
    const float* Whh  = (const float*)d_in[6];
    const float* bih  = (const float*)d_in[7];
    const float* bhh  = (const float*)d_in[8];
    const float* Wout = (const float*)d_in[9];
    const float* bout = (const float*)d_in[10];
    float* out = (float*)d_out;

    float* X  = (float*)d_ws;                       // [T*B, H]   = 21 MB
    float* G  = X + (size_t)TT * BB * HH;           // [T*B, 4H]  = 84 MB
    float* Hs = G + (size_t)TT * BB * G4;           // [T*B, H]   = 21 MB

    stage_x<<<dim3(TT * BB / 8), dim3(320), 0, stream>>>(ac, tok, emb, Win, bin, X);
    stage_gin<<<dim3(TT * BB / 8), dim3(256), 0, stream>>>(X, Wih, bih, bhh, G);
    stage_rec<<<dim3(BB), dim3(1024), 0, stream>>>(G, Whh, Hs);
    stage_logits<<<dim3(VV / 256, TT * BB / 16), dim3(256), 0, stream>>>(Hs, Wout, bout, out);
    stage_lsm<<<dim3(TT * BB), dim3(256), 0, stream>>>(out);
}

// Round 3
// 6205.481 us; speedup vs baseline: 4.3507x; 4.2113x over previous
//
#include <hip/hip_runtime.h>
#include <hip/hip_bf16.h>

// Problem constants
#define BB 32     // batch
#define TT 512    // time
#define AA 512    // acoustic dim
#define EE 256    // emb dim
#define HH 320    // hidden
#define VV 8192   // vocab
#define KIN 768   // A+E
#define G4 1280   // 4*H

#define NBLK 5    // blocks per batch (recurrence)
#define UPB 64    // hidden units per block
#define KS 80     // k-chunk per thread-group

__device__ __forceinline__ float sigm(float x) { return 1.f / (1.f + expf(-x)); }

// ---------------- Stage A: X[r=t*B+b][j] = tanh(concat(a,e) . W_in[j,:] + b_in[j]) ----------------
__global__ __launch_bounds__(320) void stage_x(const float* __restrict__ ac,
                                               const int* __restrict__ tok,
                                               const float* __restrict__ emb,
                                               const float* __restrict__ Win,
                                               const float* __restrict__ bin,
                                               float* __restrict__ X) {
    __shared__ float xs[8][KIN];
    const int r0 = blockIdx.x * 8;
    const int tid = threadIdx.x;
    for (int rr = 0; rr < 8; ++rr) {
        const int r = r0 + rr;
        const int t = r >> 5;
        const int b = r & 31;
        const int tk = tok[b * TT + t];
        const float4* ac4  = (const float4*)(ac + ((size_t)b * TT + t) * AA);
        const float4* emb4 = (const float4*)(emb + (size_t)tk * EE);
        float4* xs4 = (float4*)&xs[rr][0];
        for (int k4 = tid; k4 < KIN / 4; k4 += 320) {
            float4 v;
            if (k4 < AA / 4) v = ac4[k4];
            else if (tk == 0) v = make_float4(0.f, 0.f, 0.f, 0.f);
            else v = emb4[k4 - AA / 4];
            xs4[k4] = v;
        }
    }
    __syncthreads();
    const int j = tid;
    float acc[8];
    const float bj = bin[j];
#pragma unroll
    for (int rr = 0; rr < 8; ++rr) acc[rr] = bj;
    const float4* w4 = (const float4*)(Win + (size_t)j * KIN);
#pragma unroll 4
    for (int k4 = 0; k4 < KIN / 4; ++k4) {
        const float4 wv = w4[k4];
#pragma unroll
        for (int rr = 0; rr < 8; ++rr) {
            const float4 xv = ((const float4*)&xs[rr][0])[k4];
            acc[rr] += wv.x * xv.x + wv.y * xv.y + wv.z * xv.z + wv.w * xv.w;
        }
    }
#pragma unroll
    for (int rr = 0; rr < 8; ++rr)
        X[(size_t)(r0 + rr) * HH + j] = tanhf(acc[rr]);
}

// ---------------- Stage B: G[r][j] = X[r,:] . W_ih[j,:] + b_ih[j] + b_hh[j] ----------------
__global__ __launch_bounds__(256) void stage_gin(const float* __restrict__ X,
                                                 const float* __restrict__ Wih,
                                                 const float* __restrict__ bih,
                                                 const float* __restrict__ bhh,
                                                 float* __restrict__ G) {
    __shared__ float xs[8][HH];
    const int r0 = blockIdx.x * 8;
    const int tid = threadIdx.x;
    {
        const float4* src = (const float4*)(X + (size_t)r0 * HH);
        float4* dst = (float4*)&xs[0][0];
        for (int k4 = tid; k4 < 8 * HH / 4; k4 += 256) dst[k4] = src[k4];
    }
    __syncthreads();
    for (int p = 0; p < 5; ++p) {
        const int j = tid + 256 * p;
        const float bias = bih[j] + bhh[j];
        float acc[8];
#pragma unroll
        for (int rr = 0; rr < 8; ++rr) acc[rr] = bias;
        const float4* w4 = (const float4*)(Wih + (size_t)j * HH);
#pragma unroll 4
        for (int k4 = 0; k4 < HH / 4; ++k4) {
            const float4 wv = w4[k4];
#pragma unroll
            for (int rr = 0; rr < 8; ++rr) {
                const float4 xv = ((const float4*)&xs[rr][0])[k4];
                acc[rr] += wv.x * xv.x + wv.y * xv.y + wv.z * xv.z + wv.w * xv.w;
            }
        }
#pragma unroll
        for (int rr = 0; rr < 8; ++rr)
            G[(size_t)(r0 + rr) * G4 + j] = acc[rr];
    }
}

// ---------------- Stage C: LSTM recurrence, 5 blocks/batch, Whh in registers ----------------
// Block bid: batch b = bid/5, slice p = bid%5 owns hidden units [p*64, p*64+64).
// Thread tid: r = tid&255 (gate-row within slice: q=r>>6 gate, u=r&63 unit),
//             g = tid>>8 (k-chunk [g*80, g*80+80)).  80 weights in VGPRs.
// Cross-block h exchange per step via double-buffered hbuf + per-batch counter.
__global__ __launch_bounds__(1024, 4) void stage_rec(const float* __restrict__ G,
                                                     const float* __restrict__ Whh,
                                                     float* __restrict__ Hs,
                                                     float* __restrict__ hbuf,   // [2][BB][HH]
                                                     int* __restrict__ cnt) {    // [BB*32] padded
    const int bid = blockIdx.x;
    const int b = bid / NBLK;
    const int p = bid % NBLK;
    const int U0 = p * UPB;
    const int tid = threadIdx.x;
    const int r = tid & 255;
    const int g = tid >> 8;           // 0..3
    const int q = r >> 6;             // gate 0..3
    const int u = r & 63;             // unit within slice
    const int j = q * HH + U0 + u;    // global gate row in [0,1280)

    __shared__ float hs[HH];
    __shared__ float part[4][256];
    __shared__ float gates[256];
    __shared__ float cs[UPB];

    // preload Whh[j][g*80 .. g*80+79] into registers (one-time)
    float w[KS];
    {
        const float4* wp = (const float4*)(Whh + (size_t)j * HH + g * KS);
#pragma unroll
        for (int k4 = 0; k4 < KS / 4; ++k4) {
            const float4 v = wp[k4];
            w[4 * k4 + 0] = v.x; w[4 * k4 + 1] = v.y;
            w[4 * k4 + 2] = v.z; w[4 * k4 + 3] = v.w;
        }
    }
    if (tid < UPB) cs[tid] = 0.f;
    int* cnt_b = cnt + b * 32;   // padded: one cacheline per batch

    for (int t = 0; t < TT; ++t) {
        // prefetch this step's G row chunk (independent of h)
        float gin = 0.f;
        if (tid < 256) gin = G[((size_t)t * BB + b) * G4 + j];

        if (t > 0) {
            if (tid == 0) {
                const int target = NBLK * t;
                while (__hip_atomic_load(cnt_b, __ATOMIC_RELAXED, __HIP_MEMORY_SCOPE_AGENT) < target)
                    __builtin_amdgcn_s_sleep(1);
                __threadfence();   // acquire: invalidate L1/L2 so h reads are fresh
            }
            __syncthreads();
            // stage full h into LDS
            if (tid < HH / 4) {
                const float4* src = (const float4*)(hbuf + ((size_t)(t & 1) * BB + b) * HH);
                ((float4*)hs)[tid] = src[tid];
            }
            __syncthreads();
            // partial dot: 80 register FMAs, h broadcast from LDS
            float acc = 0.f;
            const float4* h4 = (const float4*)(hs + g * KS);
#pragma unroll
            for (int k4 = 0; k4 < KS / 4; ++k4) {
                const float4 hv = h4[k4];
                acc += w[4 * k4 + 0] * hv.x + w[4 * k4 + 1] * hv.y +
                       w[4 * k4 + 2] * hv.z + w[4 * k4 + 3] * hv.w;
            }
            part[g][r] = acc;
            __syncthreads();
            if (tid < 256)
                gates[tid] = part[0][tid] + part[1][tid] + part[2][tid] + part[3][tid] + gin;
        } else {
            if (tid < 256) gates[tid] = gin;   // h == 0 at t=0
        }
        __syncthreads();

        if (tid < UPB) {
            const float gi = gates[tid];
            const float gf = gates[64 + tid];
            const float gg = gates[128 + tid];
            const float go = gates[192 + tid];
            const float cn = sigm(gf) * cs[tid] + sigm(gi) * tanhf(gg);
            const float hn = sigm(go) * tanhf(cn);
            cs[tid] = cn;
            Hs[((size_t)t * BB + b) * HH + U0 + tid] = hn;
            __hip_atomic_store(hbuf + ((size_t)((t + 1) & 1) * BB + b) * HH + U0 + tid, hn,
                               __ATOMIC_RELAXED, __HIP_MEMORY_SCOPE_AGENT);
        }
        __syncthreads();
        if (tid == 0) {
            __threadfence();   // release: h-slice visible before count bump
            __hip_atomic_fetch_add(cnt_b, 1, __ATOMIC_RELAXED, __HIP_MEMORY_SCOPE_AGENT);
        }
    }
}

// ---------------- Stage D: logits[m=b*T+t][v] = Hs[t*B+b,:] . W_out[v,:] + b_out[v] ----------------
__global__ __launch_bounds__(256) void stage_logits(const float* __restrict__ Hs,
                                                    const float* __restrict__ Wout,
                                                    const float* __restrict__ bout,
                                                    float* __restrict__ out) {
    __shared__ float hsm[16][HH];
    const int m0 = blockIdx.y * 16;
    const int v0 = blockIdx.x * 256;
    const int tid = threadIdx.x;
    for (int rr = 0; rr < 16; ++rr) {
        const int m = m0 + rr;
        const int bb = m >> 9;
        const int t2 = m & 511;
        const float4* src = (const float4*)(Hs + ((size_t)t2 * BB + bb) * HH);
        float4* dst = (float4*)&hsm[rr][0];
        for (int k4 = tid; k4 < HH / 4; k4 += 256) dst[k4] = src[k4];
    }
    __syncthreads();
    const int v = v0 + tid;
    float acc[16];
    const float bv = bout[v];
#pragma unroll
    for (int rr = 0; rr < 16; ++rr) acc[rr] = bv;
    const float4* w4 = (const float4*)(Wout + (size_t)v * HH);
#pragma unroll 2
    for (int k4 = 0; k4 < HH / 4; ++k4) {
        const float4 wv = w4[k4];
#pragma unroll
        for (int rr = 0; rr < 16; ++rr) {
            const float4 hv = ((const float4*)&hsm[rr][0])[k4];
            acc[rr] += wv.x * hv.x + wv.y * hv.y + wv.z * hv.z + wv.w * hv.w;
        }
    }
#pragma unroll
    for (int rr = 0; rr < 16; ++rr)
        out[(size_t)(m0 + rr) * VV + v] = acc[rr];
}

// ---------------- Stage E: in-place log_softmax over V per row ----------------
__global__ __launch_bounds__(256) void stage_lsm(float* __restrict__ out) {
    __shared__ float buf[VV];
    __shared__ float red[16];
    const size_t m = blockIdx.x;
    float4* row4 = (float4*)(out + m * VV);
    float4* buf4 = (float4*)buf;
    const int tid = threadIdx.x;

    float mx = -INFINITY;
    for (int k4 = tid; k4 < VV / 4; k4 += 256) {
        const float4 v = row4[k4];
        buf4[k4] = v;
        mx = fmaxf(mx, fmaxf(fmaxf(v.x, v.y), fmaxf(v.z, v.w)));
    }
#pragma unroll
    for (int off = 32; off > 0; off >>= 1) mx = fmaxf(mx, __shfl_down(mx, off, 64));
    if ((tid & 63) == 0) red[tid >> 6] = mx;
    __syncthreads();
    if (tid == 0) {
        float m2 = red[0];
        for (int i = 1; i < 4; ++i) m2 = fmaxf(m2, red[i]);
        red[0] = m2;
    }
    __syncthreads();
    mx = red[0];

    float s = 0.f;
    for (int k4 = tid; k4 < VV / 4; k4 += 256) {
        const float4 v = buf4[k4];
        s += expf(v.x - mx) + expf(v.y - mx) + expf(v.z - mx) + expf(v.w - mx);
    }
#pragma unroll
    for (int off = 32; off > 0; off >>= 1) s += __shfl_down(s, off, 64);
    if ((tid & 63) == 0) red[8 + (tid >> 6)] = s;
    __syncthreads();
    if (tid == 0) {
        float s2 = 0.f;
        for (int i = 0; i < 4; ++i) s2 += red[8 + i];
        red[8] = logf(s2);
    }
    __syncthreads();
    const float lse = mx + red[8];
    for (int k4 = tid; k4 < VV / 4; k4 += 256) {
        float4 v = buf4[k4];
        v.x -= lse; v.y -= lse; v.z -= lse; v.w -= lse;
        row4[k4] = v;
    }
}

extern "C" void kernel_launch(void* const* d_in, const int* in_sizes, int n_in,
                              void* d_out, int out_size, void* d_ws, size_t ws_size,
                              hipStream_t stream) {
    const float* ac   = (const float*)d_in[0];
    const int*   tok  = (const int*)d_in[1];
    const float* emb  = (const float*)d_in[2];
    const float* Win  = (const float*)d_in[3];
    const float* bin  = (const float*)d_in[4];
    const float* Wih  = (const float*)d_in[5];
    const float* Whh  = (const float*)d_in[6];
    const float* bih  = (const float*)d_in[7];
    const float* bhh  = (const float*)d_in[8];
    const float* Wout = (const float*)d_in[9];
    const float* bout = (const float*)d_in[10];
    float* out = (float*)d_out;

    float* X  = (float*)d_ws;                       // [T*B, H]   = 21 MB
    float* G  = X + (size_t)TT * BB * HH;           // [T*B, 4H]  = 84 MB
    float* Hs = G + (size_t)TT * BB * G4;           // [T*B, H]   = 21 MB
    // hbuf/cnt ALIAS the X region (X is dead after stage_gin):
    float* hbuf = X;                                // [2][BB][HH] = 80 KB
    int*   cnt  = (int*)(X + 2 * BB * HH);          // [BB*32] = 4 KB (padded)

    stage_x<<<dim3(TT * BB / 8), dim3(320), 0, stream>>>(ac, tok, emb, Win, bin, X);
    stage_gin<<<dim3(TT * BB / 8), dim3(256), 0, stream>>>(X, Wih, bih, bhh, G);
    // zero the sync counters AFTER stage_gin (they alias X), BEFORE stage_rec
    hipMemsetAsync(cnt, 0, BB * 32 * sizeof(int), stream);
    stage_rec<<<dim3(BB * NBLK), dim3(1024), 0, stream>>>(G, Whh, Hs, hbuf, cnt);
    stage_logits<<<dim3(VV / 256, TT * BB / 16), dim3(256), 0, stream>>>(Hs, Wout, bout, out);
    stage_lsm<<<dim3(TT * BB), dim3(256), 0, stream>>>(out);
}